// Round 6
// baseline (231.928 us; speedup 1.0000x reference)
//
#include <hip/hip_runtime.h>
#include <stdint.h>
#include <stddef.h>

#define S_LEN 2048
#define NB    2
#define DM    1024
#define NH    16
#define DKH   64
#define NTOK  4096      // NB*S_LEN
#define QKV_N 3072
#define QSCALE 0.18033688f   // (1/8) * log2(e), folded into q in gemm epilogue

typedef __attribute__((ext_vector_type(4))) float floatx4;
using half2v = __attribute__((ext_vector_type(2))) _Float16;
using half4v = __attribute__((ext_vector_type(4))) _Float16;
using half8v = __attribute__((ext_vector_type(8))) _Float16;
using fp16x2 = __attribute__((ext_vector_type(2))) __fp16;

#if __has_builtin(__builtin_amdgcn_exp2f)
#define EXP2F __builtin_amdgcn_exp2f
#else
#define EXP2F exp2f
#endif

__device__ __forceinline__ void glds16(const void* g, void* l) {
    __builtin_amdgcn_global_load_lds((const __attribute__((address_space(1))) void*)g,
                                     (__attribute__((address_space(3))) void*)l,
                                     16, 0, 0);
}

// ---------------- cast f32 -> f16 ----------------
__global__ __launch_bounds__(256) void cast_f16_kernel(const float* __restrict__ in,
                                                       _Float16* __restrict__ out, int n4) {
    int i = blockIdx.x * blockDim.x + threadIdx.x;
    if (i < n4) {
        float4 v = ((const float4*)in)[i];
        half4v o = {(_Float16)v.x, (_Float16)v.y, (_Float16)v.z, (_Float16)v.w};
        ((half4v*)out)[i] = o;
    }
}

// ---------------- transpose + cast: in [R][C] f32 -> out [C][R] f16 ----------------
__global__ __launch_bounds__(1024) void transpose_cast_kernel(const float* __restrict__ in,
                                                              _Float16* __restrict__ out,
                                                              int R, int C) {
    __shared__ float t[32][33];
    int c0 = blockIdx.x * 32, r0 = blockIdx.y * 32;
    int x = threadIdx.x, y = threadIdx.y;
    t[y][x] = in[(size_t)(r0 + y) * C + c0 + x];
    __syncthreads();
    out[(size_t)(c0 + y) * R + r0 + x] = (_Float16)t[x][y];
}

// ---------------- mask all-ones check (flag pre-set nonzero via hipMemsetAsync) ----------------
__global__ __launch_bounds__(256) void mask_reduce_kernel(const int* __restrict__ mask,
                                                          int* __restrict__ f, int n4) {
    int i = blockIdx.x * blockDim.x + threadIdx.x;
    if (i < n4) {
        int4 v = ((const int4*)mask)[i];
        if (v.x == 0 || v.y == 0 || v.z == 0 || v.w == 0) *f = 0;
    }
}

// ---------------- V transpose: qkv v-part [s][d] -> vt [b][h][d][s], f16 ----------------
__global__ __launch_bounds__(256) void transpose_v_kernel(const _Float16* __restrict__ qkv,
                                                          _Float16* __restrict__ vt) {
    __shared__ _Float16 t[64][68];
    int st = blockIdx.x * 64, h = blockIdx.y, b = blockIdx.z;
    int tid = threadIdx.x;
    #pragma unroll
    for (int p = 0; p < 4; ++p) {
        int idx = p * 1024 + tid * 4;
        int sl = idx >> 6, d0 = idx & 63;
        half4v v = *(const half4v*)(qkv + (size_t)(b * S_LEN + st + sl) * QKV_N + 2 * DM + h * DKH + d0);
        t[d0 + 0][sl] = v.x; t[d0 + 1][sl] = v.y; t[d0 + 2][sl] = v.z; t[d0 + 3][sl] = v.w;
    }
    __syncthreads();
    #pragma unroll
    for (int p = 0; p < 4; ++p) {
        int idx = p * 1024 + tid * 4;
        int d = idx >> 6, s0 = idx & 63;
        half4v v = {t[d][s0], t[d][s0 + 1], t[d][s0 + 2], t[d][s0 + 3]};
        *(half4v*)(vt + ((size_t)(b * NH + h) * DKH + d) * S_LEN + st + s0) = v;
    }
}

// ---------------- GEMM: C[M][N] = A[M][K] @ Bt[N][K]^T + bias ----------------
// FINAL=0 (qkv): f16 out row-major; n<DM scaled by QSCALE. FINAL=1: fp32 out.
template <int FINAL, int BN>
__global__ __launch_bounds__(256) void gemm_bt_kernel(const _Float16* __restrict__ A,
                                                      const _Float16* __restrict__ Bt,
                                                      const float* __restrict__ bias,
                                                      float* __restrict__ Cf,
                                                      _Float16* __restrict__ Ch,
                                                      int M, int N, int K) {
    constexpr int NJ = BN / 32;
    __shared__ _Float16 As[128 * 64];
    __shared__ _Float16 Bs[BN * 64];

    const int nt = blockIdx.x, mt = blockIdx.y;
    const int tid = threadIdx.x, wave = tid >> 6, lane = tid & 63;
    const int quad = lane >> 4, l16 = lane & 15;
    const int wm = wave >> 1, wn = wave & 1;

    floatx4 acc[4][NJ];
    #pragma unroll
    for (int i = 0; i < 4; ++i)
        #pragma unroll
        for (int j = 0; j < NJ; ++j)
            #pragma unroll
            for (int r = 0; r < 4; ++r) acc[i][j][r] = 0.0f;

    const _Float16* Ab = A + (size_t)mt * 128 * K;
    const _Float16* Bb = Bt + (size_t)nt * BN * K;

    for (int kt = 0; kt < K; kt += 64) {
        #pragma unroll
        for (int p = 0; p < 4; ++p) {
            int slot = p * 256 + wave * 64 + lane;
            int row = slot >> 3, cc = slot & 7, c = cc ^ (row & 7);
            glds16(Ab + (size_t)row * K + kt + c * 8, As + (size_t)(p * 256 + wave * 64) * 8);
        }
        #pragma unroll
        for (int p = 0; p < BN / 32; ++p) {
            int slot = p * 256 + wave * 64 + lane;
            int row = slot >> 3, cc = slot & 7, c = cc ^ (row & 7);
            glds16(Bb + (size_t)row * K + kt + c * 8, Bs + (size_t)(p * 256 + wave * 64) * 8);
        }
        __syncthreads();

        #pragma unroll
        for (int kk = 0; kk < 2; ++kk) {
            half8v af[4], bfr[NJ];
            #pragma unroll
            for (int i = 0; i < 4; ++i) {
                int row = wm * 64 + i * 16 + l16;
                int c = (kk * 4 + quad) ^ (row & 7);
                af[i] = *(const half8v*)(As + row * 64 + c * 8);
            }
            #pragma unroll
            for (int j = 0; j < NJ; ++j) {
                int row = wn * (BN / 2) + j * 16 + l16;
                int c = (kk * 4 + quad) ^ (row & 7);
                bfr[j] = *(const half8v*)(Bs + row * 64 + c * 8);
            }
            #pragma unroll
            for (int i = 0; i < 4; ++i)
                #pragma unroll
                for (int j = 0; j < NJ; ++j)
                    acc[i][j] = __builtin_amdgcn_mfma_f32_16x16x32_f16(af[i], bfr[j], acc[i][j], 0, 0, 0);
        }
        __syncthreads();
    }

    #pragma unroll
    for (int j = 0; j < NJ; ++j) {
        int n = nt * BN + wn * (BN / 2) + j * 16 + l16;
        float bv = bias[n];
        float sc = (!FINAL && n < DM) ? QSCALE : 1.0f;
        #pragma unroll
        for (int i = 0; i < 4; ++i) {
            int m0 = mt * 128 + wm * 64 + i * 16 + quad * 4;
            #pragma unroll
            for (int r = 0; r < 4; ++r) {
                float v = (acc[i][j][r] + bv) * sc;
                if (FINAL) Cf[(size_t)(m0 + r) * N + n] = v;
                else       Ch[(size_t)(m0 + r) * QKV_N + n] = (_Float16)v;
            }
        }
    }
}

// ---------------- flash attention v5: k-split (2 blocks per (bh,qt)), 4 blocks/CU ----------------
// Each block: 128 q x 1024 keys (8 epochs of 128). Emits normalized f16 partial O + denominator.
// S^T = mfma_x32(A=K, B=Q): C-layout lane=q(l16), reg r -> s=16j+quad*4+r,
// which IS the A-fragment layout of mfma_f32_16x16x16f16 -> PV from regs.
__global__ __launch_bounds__(256) void flash_kernel(const _Float16* __restrict__ qkv,
                                                    const _Float16* __restrict__ vt,
                                                    const int* __restrict__ mask,
                                                    const int* __restrict__ flag,
                                                    _Float16* __restrict__ Opart,
                                                    float* __restrict__ Lpart) {
    __shared__ _Float16 Ks[128 * 64];   // [s-row][d], granule swizzle ^(row&7)
    __shared__ _Float16 Vs[64 * 128];   // [d-row][s], granule swizzle ^(row&15)

    const int bh = blockIdx.x, qt = blockIdx.y, ks = blockIdx.z;
    const int b = bh >> 4, h = bh & 15;
    const int tid = threadIdx.x, wave = tid >> 6, lane = tid & 63;
    const int quad = lane >> 4, l16 = lane & 15;
    const int allones = (*flag != 0);

    // Q B-fragments for the wave's two 16-q halves (q pre-scaled by QSCALE)
    const _Float16* qrow0 = qkv + (size_t)(b * S_LEN + qt * 128 + wave * 32 + l16) * QKV_N + h * DKH;
    const _Float16* qrow1 = qrow0 + (size_t)16 * QKV_N;
    half8v qa0 = *(const half8v*)(qrow0 + quad * 8);
    half8v qa1 = *(const half8v*)(qrow0 + 32 + quad * 8);
    half8v qb0 = *(const half8v*)(qrow1 + quad * 8);
    half8v qb1 = *(const half8v*)(qrow1 + 32 + quad * 8);

    const _Float16* kbase = qkv + (size_t)b * S_LEN * QKV_N + DM + h * DKH;
    const _Float16* vbase = vt + (size_t)(b * NH + h) * DKH * S_LEN;

    floatx4 oa[4], ob[4];
    #pragma unroll
    for (int c = 0; c < 4; ++c)
        #pragma unroll
        for (int r = 0; r < 4; ++r) { oa[c][r] = 0.0f; ob[c][r] = 0.0f; }
    float lsa = 0.0f, lsb = 0.0f;

    for (int kt = ks * 8; kt < ks * 8 + 8; ++kt) {
        // stage K tile: 128 rows x 8 granules
        #pragma unroll
        for (int p = 0; p < 4; ++p) {
            int slot = p * 256 + wave * 64 + lane;
            int row = slot >> 3, cc = slot & 7, c = cc ^ (row & 7);
            glds16(kbase + (size_t)(kt * 128 + row) * QKV_N + c * 8,
                   Ks + (size_t)(p * 256 + wave * 64) * 8);
        }
        // stage V^T tile: 64 rows x 16 granules
        #pragma unroll
        for (int p = 0; p < 4; ++p) {
            int slot = p * 256 + wave * 64 + lane;
            int row = slot >> 4, cc = slot & 15, c = cc ^ (row & 15);
            glds16(vbase + (size_t)row * S_LEN + kt * 128 + c * 8,
                   Vs + (size_t)(p * 256 + wave * 64) * 8);
        }
        __syncthreads();

        // S^T tiles for both q-halves; K A-fragments loaded once
        half4v pa[8], pb[8];
        #pragma unroll
        for (int j = 0; j < 8; ++j) {
            int rowk = j * 16 + l16;
            half8v a0 = *(const half8v*)(Ks + rowk * 64 + ((quad) ^ (rowk & 7)) * 8);
            half8v a1 = *(const half8v*)(Ks + rowk * 64 + ((4 + quad) ^ (rowk & 7)) * 8);
            floatx4 za, zb;
            #pragma unroll
            for (int r = 0; r < 4; ++r) { za[r] = 0.0f; zb[r] = 0.0f; }
            za = __builtin_amdgcn_mfma_f32_16x16x32_f16(a0, qa0, za, 0, 0, 0);
            za = __builtin_amdgcn_mfma_f32_16x16x32_f16(a1, qa1, za, 0, 0, 0);
            zb = __builtin_amdgcn_mfma_f32_16x16x32_f16(a0, qb0, zb, 0, 0, 0);
            zb = __builtin_amdgcn_mfma_f32_16x16x32_f16(a1, qb1, zb, 0, 0, 0);

            if (!allones) {  // general-mask slow path
                for (int r = 0; r < 4; ++r) {
                    int s = kt * 128 + j * 16 + quad * 4 + r;
                    int qA = qt * 128 + wave * 32 + l16;
                    if (mask[((size_t)b * S_LEN + qA) * S_LEN + s] == 0) za[r] = -1e9f;
                    if (mask[((size_t)b * S_LEN + qA + 16) * S_LEN + s] == 0) zb[r] = -1e9f;
                }
            }

            float p0 = EXP2F(za[0]), p1 = EXP2F(za[1]), p2 = EXP2F(za[2]), p3 = EXP2F(za[3]);
            lsa += (p0 + p1) + (p2 + p3);
            fp16x2 lo = __builtin_amdgcn_cvt_pkrtz(p0, p1);
            fp16x2 hi = __builtin_amdgcn_cvt_pkrtz(p2, p3);
            half2v lo2 = __builtin_bit_cast(half2v, lo);
            half2v hi2 = __builtin_bit_cast(half2v, hi);
            half4v pka = {lo2.x, lo2.y, hi2.x, hi2.y};
            pa[j] = pka;

            p0 = EXP2F(zb[0]); p1 = EXP2F(zb[1]); p2 = EXP2F(zb[2]); p3 = EXP2F(zb[3]);
            lsb += (p0 + p1) + (p2 + p3);
            lo = __builtin_amdgcn_cvt_pkrtz(p0, p1);
            hi = __builtin_amdgcn_cvt_pkrtz(p2, p3);
            lo2 = __builtin_bit_cast(half2v, lo);
            hi2 = __builtin_bit_cast(half2v, hi);
            half4v pkb = {lo2.x, lo2.y, hi2.x, hi2.y};
            pb[j] = pkb;
        }

        // O += P V : V B-fragments loaded once, used for both halves
        #pragma unroll
        for (int j = 0; j < 8; ++j) {
            int g = 2 * j + (quad >> 1);
            #pragma unroll
            for (int c = 0; c < 4; ++c) {
                int rowv = c * 16 + l16;
                half4v bv = *(const half4v*)(Vs + rowv * 128 + ((g ^ (rowv & 15)) * 8) + (quad & 1) * 4);
                oa[c] = __builtin_amdgcn_mfma_f32_16x16x16f16(pa[j], bv, oa[c], 0, 0, 0);
                ob[c] = __builtin_amdgcn_mfma_f32_16x16x16f16(pb[j], bv, ob[c], 0, 0, 0);
            }
        }
        __syncthreads();
    }

    // reduce row sums across quads (q lives at l16), redistribute to O layout (q=quad*4+r)
    lsa += __shfl_xor(lsa, 16); lsa += __shfl_xor(lsa, 32);
    lsb += __shfl_xor(lsb, 16); lsb += __shfl_xor(lsb, 32);
    float lia[4], lib[4];
    #pragma unroll
    for (int r = 0; r < 4; ++r) {
        int src = (lane & 48) | ((lane >> 4) * 4 + r);
        float la_ = __shfl(lsa, src), lb_ = __shfl(lsb, src);
        lia[r] = la_ > 0.0f ? 1.0f / la_ : 0.0f;
        lib[r] = lb_ > 0.0f ? 1.0f / lb_ : 0.0f;
    }

    const size_t obase = ((size_t)(ks * 32 + bh) * 16 + qt) * (128 * 64);
    #pragma unroll
    for (int c = 0; c < 4; ++c)
        #pragma unroll
        for (int r = 0; r < 4; ++r) {
            int qq = wave * 32 + quad * 4 + r;
            Opart[obase + (size_t)qq * 64 + c * 16 + l16]        = (_Float16)(oa[c][r] * lia[r]);
            Opart[obase + (size_t)(qq + 16) * 64 + c * 16 + l16] = (_Float16)(ob[c][r] * lib[r]);
        }
    const int lbase = ((ks * 32 + bh) * 16 + qt) * 128;
    if (quad == 0) Lpart[lbase + wave * 32 + l16] = lsa;
    if (quad == 1) Lpart[lbase + wave * 32 + 16 + l16] = lsb;
}

// ---------------- combine: O = (Oa*la + Ob*lb) / (la+lb) -> ctx f16 ----------------
__global__ __launch_bounds__(256) void combine_kernel(const _Float16* __restrict__ Opart,
                                                      const float* __restrict__ Lpart,
                                                      _Float16* __restrict__ ctx) {
    const int bh = blockIdx.x, qt = blockIdx.y;
    const int b = bh >> 4, h = bh & 15;
    const _Float16* Oa = Opart + ((size_t)(0 * 32 + bh) * 16 + qt) * (128 * 64);
    const _Float16* Ob = Opart + ((size_t)(1 * 32 + bh) * 16 + qt) * (128 * 64);
    const float* La = Lpart + ((0 * 32 + bh) * 16 + qt) * 128;
    const float* Lb = Lpart + ((1 * 32 + bh) * 16 + qt) * 128;
    #pragma unroll
    for (int k = 0; k < 4; ++k) {
        int i8 = k * 256 + threadIdx.x;        // 1024 half8 per tile
        int q = i8 >> 3, d0 = (i8 & 7) * 8;
        float la = La[q], lb = Lb[q];
        float s = la + lb;
        float w = s > 0.0f ? 1.0f / s : 0.0f;
        float wa = la * w, wb = lb * w;
        half8v va = *(const half8v*)(Oa + (size_t)i8 * 8);
        half8v vb = *(const half8v*)(Ob + (size_t)i8 * 8);
        half8v o;
        #pragma unroll
        for (int e = 0; e < 8; ++e)
            o[e] = (_Float16)((float)va[e] * wa + (float)vb[e] * wb);
        *(half8v*)(ctx + (size_t)(b * S_LEN + qt * 128 + q) * DM + h * DKH + d0) = o;
    }
}

// ---------------- host ----------------
extern "C" void kernel_launch(void* const* d_in, const int* in_sizes, int n_in,
                              void* d_out, int out_size, void* d_ws, size_t ws_size,
                              hipStream_t stream) {
    const float* query = (const float*)d_in[0];
    const int*   mask  = (const int*)d_in[1];
    const float* W_qkv = (const float*)d_in[2];
    const float* b_qkv = (const float*)d_in[3];
    const float* W_out = (const float*)d_in[4];
    const float* b_out = (const float*)d_in[5];
    float* out = (float*)d_out;

    char* w = (char*)d_ws;
    _Float16* qh    = (_Float16*)w;  w += (size_t)NTOK * DM * 2;             // 8 MB (reused as ctx)
    _Float16* wqt   = (_Float16*)w;  w += (size_t)QKV_N * DM * 2;            // 6 MB
    _Float16* wot   = (_Float16*)w;  w += (size_t)DM * DM * 2;               // 2 MB
    _Float16* qkvh  = (_Float16*)w;  w += (size_t)NTOK * QKV_N * 2;          // 24 MB
    _Float16* vt    = (_Float16*)w;  w += (size_t)NB * NH * DKH * S_LEN * 2; // 8 MB
    _Float16* Opart = (_Float16*)w;  w += (size_t)2 * NB * NH * 16 * 128 * 64 * 2; // 16 MB
    float*    Lpart = (float*)w;     w += (size_t)2 * NB * NH * 16 * 128 * 4;      // 0.5 MB
    int*      flag  = (int*)w;
    _Float16* ctxh = qh;  // qh dead after gemm1

    cast_f16_kernel<<<(NTOK * DM / 4 + 255) / 256, 256, 0, stream>>>(query, qh, NTOK * DM / 4);
    transpose_cast_kernel<<<dim3(QKV_N / 32, DM / 32), dim3(32, 32), 0, stream>>>(W_qkv, wqt, DM, QKV_N);
    transpose_cast_kernel<<<dim3(DM / 32, DM / 32), dim3(32, 32), 0, stream>>>(W_out, wot, DM, DM);
    hipMemsetAsync(flag, 1, 4, stream);   // nonzero = assume all-ones until proven otherwise
    mask_reduce_kernel<<<(NB * S_LEN * S_LEN / 4 + 255) / 256, 256, 0, stream>>>(
        mask, flag, NB * S_LEN * S_LEN / 4);

    // qkv = query @ W_qkv + b_qkv -> f16 row-major (q scaled by QSCALE)
    gemm_bt_kernel<0, 128><<<dim3(QKV_N / 128, NTOK / 128), 256, 0, stream>>>(
        qh, wqt, b_qkv, nullptr, qkvh, NTOK, QKV_N, DM);

    // v -> vt [b][h][d][s] (coalesced LDS transpose)
    transpose_v_kernel<<<dim3(S_LEN / 64, NH, NB), 256, 0, stream>>>(qkvh, vt);

    // flash attention, k-split x2 -> normalized partials
    flash_kernel<<<dim3(NB * NH, S_LEN / 128, 2), 256, 0, stream>>>(
        qkvh, vt, mask, flag, Opart, Lpart);

    // combine partials -> ctx f16
    combine_kernel<<<dim3(NB * NH, S_LEN / 128), 256, 0, stream>>>(Opart, Lpart, ctxh);

    // out = ctx @ W_out + b_out -> fp32
    gemm_bt_kernel<1, 64><<<dim3(DM / 64, NTOK / 128), 256, 0, stream>>>(
        ctxh, wot, b_out, out, nullptr, NTOK, DM, DM);
}